// Round 4
// baseline (296.885 us; speedup 1.0000x reference)
//
#include <hip/hip_runtime.h>

typedef __attribute__((ext_vector_type(8))) short short8;
typedef __attribute__((ext_vector_type(4))) float f32x4;

__device__ __forceinline__ unsigned short f2bf(float f) {
  unsigned u = __float_as_uint(f);
  u += 0x7FFF + ((u >> 16) & 1);
  return (unsigned short)(u >> 16);
}
__device__ __forceinline__ float bf2f(unsigned short h) {
  return __uint_as_float(((unsigned)h) << 16);
}

// ---------------- kernel 1a: h2 row-sums (hbar accumulation) ----------------
// grid 8 x 256. Block bi handles coord rows [bi*32, bi*32+32). All fp32.
__global__ __launch_bounds__(256) void mlp_h2_kernel(
    const float* __restrict__ w1, const float* __restrict__ b1,
    const float* __restrict__ w2, const float* __restrict__ b2,
    float* __restrict__ hbar)
{
  __shared__ float W2T[64][65];
  __shared__ float h1s[32][64];
  __shared__ float partial[4][64];
  const int t = threadIdx.x;
  const int k = t & 63, rg = t >> 6;

  for (int v = 0; v < 16; ++v) {
    int idx = v * 256 + t;
    W2T[idx & 63][idx >> 6] = w2[idx];  // W2T[col][row] = W2[row][col]
  }
  const int r0 = blockIdx.x * 32;
  for (int v = 0; v < 8; ++v) {
    int idx = v * 256 + t;
    int rl = idx >> 6, j = idx & 63;
    int r = r0 + rl;
    float gx = (float)(r >> 4) * (1.0f / 15.0f);
    float gy = (float)(r & 15) * (1.0f / 15.0f);
    float h = gx * w1[2 * j] + gy * w1[2 * j + 1] + b1[j];
    h1s[rl][j] = fmaxf(h, 0.0f);
  }
  __syncthreads();

  float acc[8] = {0, 0, 0, 0, 0, 0, 0, 0};
  for (int j = 0; j < 64; ++j) {
    float w = W2T[j][k];
#pragma unroll
    for (int rr = 0; rr < 8; ++rr)
      acc[rr] += h1s[rg * 8 + rr][j] * w;
  }
  float b2v = b2[k];
  float s = 0.0f;
#pragma unroll
  for (int rr = 0; rr < 8; ++rr) s += fmaxf(acc[rr] + b2v, 0.0f);
  partial[rg][k] = s;
  __syncthreads();
  if (t < 64) {
    atomicAdd(&hbar[t], partial[0][t] + partial[1][t] + partial[2][t] + partial[3][t]);
  }
}

// ---------------- kernel 1b: layer 3 + mean + sigmoid ----------------
// grid 3 x 256 -> j = 0..767.  Mf[j] = sigmoid(b3[j] + (hbar/256) . W3[j])
__global__ __launch_bounds__(256) void mlp_out_kernel(
    const float* __restrict__ w3, const float* __restrict__ b3,
    const float* __restrict__ hbar, float* __restrict__ wsM,
    float* __restrict__ outMf)
{
  int j = blockIdx.x * 256 + threadIdx.x;  // 0..767
  float s = 0.0f;
  for (int kk = 0; kk < 64; ++kk)
    s += hbar[kk] * w3[j * 64 + kk];
  float o = b3[j] + s * (1.0f / 256.0f);
  float m = 1.0f / (1.0f + expf(-o));
  wsM[j] = m;
  outMf[j] = m;  // fp32 output
}

// ---------------- main kernel: per-patch DCT/mask/IDCT via MFMA ----------------
// One wave = 8 horizontally-adjacent patches of one (b, c, ph).
// grid 3072 x 256  (12288 waves = 32b * 3c * 32ph * 4 pw-groups)
__global__ __launch_bounds__(256) void dct_main_kernel(
    const float* __restrict__ x,
    const float* __restrict__ wsM,
    float* __restrict__ out)
{
  __shared__ uint4 lds_buf[4][400];  // per wave: 8 patches x 800 B (bf16, row stride 48 B)
  const int lane = threadIdx.x & 63;
  const int wib = threadIdx.x >> 6;
  unsigned char* my = (unsigned char*)lds_buf[wib];

  int wave_id = blockIdx.x * 4 + wib;
  const int pwg = wave_id & 3;
  int tt = wave_id >> 2;
  const int ph = tt & 31;
  tt >>= 5;
  const int c = tt % 3;
  const int b = tt / 3;

  const int n = lane & 15;
  const int g = lane >> 4;

  size_t xbase = (((size_t)(b * 3 + c) * 512) + (size_t)ph * 16) * 512 + (size_t)pwg * 128;

  // ---- stage 16 rows x 128 cols (fp32 -> bf16) to LDS: patch p row j at p*800 + j*48
  {
    const float* srcf = x + xbase;
    const int r2 = lane >> 5;   // row within pair
    const int cc = lane & 31;   // 4-float chunk within the 128-col row
    const int p = cc >> 2, c4 = cc & 3;
#pragma unroll
    for (int v = 0; v < 8; ++v) {
      float4 f = *(const float4*)(srcf + (size_t)(2 * v + r2) * 512 + cc * 4);
      unsigned lo = (unsigned)f2bf(f.x) | ((unsigned)f2bf(f.y) << 16);
      unsigned hi = (unsigned)f2bf(f.z) | ((unsigned)f2bf(f.w) << 16);
      *(uint2*)(my + p * 800 + (2 * v + r2) * 48 + c4 * 8) = make_uint2(lo, hi);
    }
  }

  // ---- mask values (fp32) for this lane's (row=n, cols 4g..4g+3), channel c
  f32x4 Mv;
  {
    const float* mp = wsM + c * 256 + n * 16 + 4 * g;
    Mv[0] = mp[0]; Mv[1] = mp[1]; Mv[2] = mp[2]; Mv[3] = mp[3];
  }

  // ---- D operands (bf16). D[i][k] = s(i)*cos(pi*(2i+1)k/32), s(0)=0.25 else sqrt(2)/4
  // (exactly the reference's row-0-scaled, non-orthogonal construction).
  short8 B1, B2, B3;
  {
    const float PIc = 3.14159265358979323846f;
    const float SC = 0.35355339059327373f;
#pragma unroll
    for (int j = 0; j < 8; ++j) {
      int kk = 8 * g + j;
      float v = 0.0f;
      if (kk < 16) {  // B1[k][n] = D^T[k][n] = D[n][k]; K-rows 16..31 zero
        float sc = (n == 0) ? 0.25f : SC;
        v = sc * cosf(PIc * (float)((2 * n + 1) * kk) * (1.0f / 32.0f));
      }
      B1[j] = (short)f2bf(v);
    }
#pragma unroll
    for (int j = 0; j < 4; ++j) {  // row-interleaved for the C-as-A transpose trick
      int r = 4 * g + j;
      float sc_n = (n == 0) ? 0.25f : SC;
      B2[j] = (short)f2bf(sc_n * cosf(PIc * (float)((2 * n + 1) * r) * (1.0f / 32.0f)));  // D^T[r][n]
      float sc_r = (r == 0) ? 0.25f : SC;
      B3[j] = (short)f2bf(sc_r * cosf(PIc * (float)((2 * r + 1) * n) * (1.0f / 32.0f)));  // D[r][n]
      B2[j + 4] = 0;
      B3[j + 4] = 0;
    }
  }

  __syncthreads();

  const f32x4 zero4 = {0.f, 0.f, 0.f, 0.f};
  size_t obase0 = ((((size_t)b * 1024 + (size_t)ph * 32 + pwg * 8) * 3) + c) * 256 + n * 16 + 4 * g;
  float* resp = out;
  float* recp = out + (size_t)25165824;

  for (int p = 0; p < 8; ++p) {
    const unsigned char* pb = my + p * 800;

    // S1 = P * D^T
    short8 A1 = {0, 0, 0, 0, 0, 0, 0, 0};
    if (lane < 32) {
      uint4 t4 = *(const uint4*)(pb + n * 48 + g * 16);
      A1 = __builtin_bit_cast(short8, t4);
    }
    f32x4 s1 = __builtin_amdgcn_mfma_f32_16x16x32_bf16(A1, B1, zero4, 0, 0, 0);

    // S2 = S1^T * D^T = Dcoeff^T  (C-regs fed back as A == transpose)
    short8 A2 = {(short)f2bf(s1[0]), (short)f2bf(s1[1]), (short)f2bf(s1[2]), (short)f2bf(s1[3]), 0, 0, 0, 0};
    f32x4 s2 = __builtin_amdgcn_mfma_f32_16x16x32_bf16(A2, B2, zero4, 0, 0, 0);

    // mask (fp32), then S3 = Dmasked * D
    short8 A3 = {(short)f2bf(s2[0] * Mv[0]), (short)f2bf(s2[1] * Mv[1]),
                 (short)f2bf(s2[2] * Mv[2]), (short)f2bf(s2[3] * Mv[3]), 0, 0, 0, 0};
    f32x4 s3 = __builtin_amdgcn_mfma_f32_16x16x32_bf16(A3, B3, zero4, 0, 0, 0);

    // S4 = S3^T * D = recon^T : lane holds recon[n][4g+q], q=0..3 (row-adjacent)
    short8 A4 = {(short)f2bf(s3[0]), (short)f2bf(s3[1]), (short)f2bf(s3[2]), (short)f2bf(s3[3]), 0, 0, 0, 0};
    f32x4 s4 = __builtin_amdgcn_mfma_f32_16x16x32_bf16(A4, B3, zero4, 0, 0, 0);

    // residual = P - recon  (P[n][4g..4g+3] is one 8B LDS read)
    uint2 pv = *(const uint2*)(pb + n * 48 + 8 * g);
    float p0 = bf2f((unsigned short)(pv.x & 0xFFFF));
    float p1 = bf2f((unsigned short)(pv.x >> 16));
    float p2 = bf2f((unsigned short)(pv.y & 0xFFFF));
    float p3 = bf2f((unsigned short)(pv.y >> 16));

    size_t ob = obase0 + (size_t)p * 768;  // next patch: +3*256 elems
    float4 rv = make_float4(p0 - s4[0], p1 - s4[1], p2 - s4[2], p3 - s4[3]);
    float4 cv = make_float4(s4[0], s4[1], s4[2], s4[3]);
    *(float4*)(resp + ob) = rv;   // fp32 outputs, 16 B/lane, fully coalesced per patch
    *(float4*)(recp + ob) = cv;
  }
}

extern "C" void kernel_launch(void* const* d_in, const int* in_sizes, int n_in,
                              void* d_out, int out_size, void* d_ws, size_t ws_size,
                              hipStream_t stream) {
  const float* x  = (const float*)d_in[0];
  const float* w1 = (const float*)d_in[1];
  const float* b1 = (const float*)d_in[2];
  const float* w2 = (const float*)d_in[3];
  const float* b2 = (const float*)d_in[4];
  const float* w3 = (const float*)d_in[5];
  const float* b3 = (const float*)d_in[6];
  float* out = (float*)d_out;

  float* ws = (float*)d_ws;
  float* wsM = ws;             // 768 floats: Mf fp32
  float* hbar = ws + 768;      // 64 floats

  hipMemsetAsync(hbar, 0, 64 * sizeof(float), stream);
  mlp_h2_kernel<<<8, 256, 0, stream>>>(w1, b1, w2, b2, hbar);
  mlp_out_kernel<<<3, 256, 0, stream>>>(w3, b3, hbar, wsM, out + (size_t)50331648);
  dct_main_kernel<<<3072, 256, 0, stream>>>(x, wsM, out);
}